// Round 2
// baseline (351.231 us; speedup 1.0000x reference)
//
#include <hip/hip_runtime.h>

#define N_RAYS 262144
#define N_PTS  64
#define FAR_DELTA 1e10f
// 256 threads = 4 waves; each wave handles 4 rays (16 lanes/ray, 4 samples/lane)
#define RAYS_PER_BLOCK 16

__global__ __launch_bounds__(256) void volume_render_kernel(
    const float* __restrict__ density,       // (N, 64, 1)
    const float* __restrict__ depth_values,  // (N, 64)
    const float* __restrict__ rays_feature,  // (N, 64, 3)
    float* __restrict__ out)                 // feature (N*3) then depth (N)
{
    const int lane = threadIdx.x & 63;
    const int wave = threadIdx.x >> 6;
    const int sub  = lane >> 4;        // which of the wave's 4 rays
    const int l    = lane & 15;        // position within the 16-lane ray group
    const int ray  = blockIdx.x * RAYS_PER_BLOCK + wave * 4 + sub;

    // depth & density: one float4 per lane; the whole wave's access is
    // 1024 contiguous bytes per instruction (perfect coalescing).
    const float4 d  = ((const float4*)depth_values)[(long)ray * 16 + l];
    const float4 sg = ((const float4*)density)[(long)ray * 16 + l];

    // feature: lane l owns samples 4l..4l+3 -> floats 12l..12l+11 of the
    // ray's 192-float block = 3 float4 loads, and every element is
    // LANE-LOCAL to its sample's weight (no gather shuffles needed).
    const float4* fp = (const float4*)rays_feature + (long)ray * 48 + l * 3;
    const float4 fa = fp[0];   // s0.x s0.y s0.z s1.x
    const float4 fb = fp[1];   // s1.y s1.z s2.x s2.y
    const float4 fc = fp[2];   // s2.z s3.x s3.y s3.z

    // deltas: in-lane diffs + one boundary value from the next lane
    const float dnx = __shfl_down(d.x, 1, 16);
    const float dl0 = d.y - d.x;
    const float dl1 = d.z - d.y;
    const float dl2 = d.w - d.z;
    const float dl3 = (l == 15) ? FAR_DELTA : (dnx - d.w);

    // per-segment transmittance e_i = exp(-sigma_i * delta_i)
    const float e0 = __expf(-sg.x * dl0);
    const float e1 = __expf(-sg.y * dl1);
    const float e2 = __expf(-sg.z * dl2);
    const float e3 = __expf(-sg.w * dl3);   // lane 15: exp(-~1e10) -> 0, fine

    // lane-local exclusive products q_i = prod_{j<i} e_j (q0 = 1)
    const float q1 = e0;
    const float q2 = q1 * e1;
    const float q3 = q2 * e2;

    // segmented (16-lane) exclusive multiplicative scan of the lane totals.
    // Matches the reference cumprod structure exactly.
    float ptot = q3 * e3;
    #pragma unroll
    for (int off = 1; off < 16; off <<= 1) {
        float t = __shfl_up(ptot, off, 16);
        if (l >= off) ptot *= t;
    }
    float p_exc = __shfl_up(ptot, 1, 16);   // lane 15's total never consumed
    if (l == 0) p_exc = 1.0f;

    // weights w_i = T_i * (1 - e_i), T_i = p_exc * q_i
    const float w0 = p_exc *      (1.0f - e0);
    const float w1 = p_exc * q1 * (1.0f - e1);
    const float w2 = p_exc * q2 * (1.0f - e2);
    const float w3 = p_exc * q3 * (1.0f - e3);

    // fully lane-local weighted feature / depth partials
    float fx = w0*fa.x + w1*fa.w + w2*fb.z + w3*fc.y;
    float fy = w0*fa.y + w1*fb.x + w2*fb.w + w3*fc.z;
    float fz = w0*fa.z + w1*fb.y + w2*fc.x + w3*fc.w;
    float wd = w0*d.x  + w1*d.y  + w2*d.z  + w3*d.w;

    // 16-lane butterfly reduction (4 steps x 4 accumulators)
    #pragma unroll
    for (int off = 8; off > 0; off >>= 1) {
        fx += __shfl_xor(fx, off, 16);
        fy += __shfl_xor(fy, off, 16);
        fz += __shfl_xor(fz, off, 16);
        wd += __shfl_xor(wd, off, 16);
    }

    // epilogue: lanes 0..2 of each group store xyz (12 consecutive floats
    // per wave), lane 3 stores depth (4 consecutive floats per wave)
    if (l < 3) {
        const float v = (l == 0) ? fx : ((l == 1) ? fy : fz);
        out[(long)ray * 3 + l] = v;
    } else if (l == 3) {
        out[(long)N_RAYS * 3 + ray] = wd;
    }
}

extern "C" void kernel_launch(void* const* d_in, const int* in_sizes, int n_in,
                              void* d_out, int out_size, void* d_ws, size_t ws_size,
                              hipStream_t stream) {
    const float* density      = (const float*)d_in[0];
    const float* depth_values = (const float*)d_in[1];
    const float* rays_feature = (const float*)d_in[2];
    float* out = (float*)d_out;

    const int blocks = N_RAYS / RAYS_PER_BLOCK;  // 16384
    volume_render_kernel<<<blocks, 256, 0, stream>>>(
        density, depth_values, rays_feature, out);
}